// Round 6
// baseline (531.714 us; speedup 1.0000x reference)
//
#include <hip/hip_runtime.h>
#include <hip/hip_fp16.h>

typedef _Float16 half8 __attribute__((ext_vector_type(8)));
typedef float f32x4 __attribute__((ext_vector_type(4)));

__device__ __forceinline__ float tanh_fast(float x) {
  float e = __expf(2.0f * x);
  return 1.0f - 2.0f / (e + 1.0f);
}

__device__ __forceinline__ void gload16(const _Float16* g, _Float16* l) {
  __builtin_amdgcn_global_load_lds((const __attribute__((address_space(1))) void*)g,
                                   (__attribute__((address_space(3))) void*)l,
                                   16, 0, 0);
}

// ---------------- merged setup: transpose input_v -> Vt fp16, Wv_att -> Wh fp16
// (padded 1280 rows), and all bias-inits (wgt, xq_raw, qfus_raw, vfus_raw, x_out).
__global__ __launch_bounds__(256) void k_misc(const float* __restrict__ in_v,
                                              _Float16* __restrict__ Vt,
                                              const float* __restrict__ Wv,
                                              _Float16* __restrict__ Wh,
                                              const float* __restrict__ batt,
                                              const float* __restrict__ bq_att,
                                              const float* __restrict__ bq_fus,
                                              const float* __restrict__ bv_fus,
                                              const float* __restrict__ bc,
                                              float* __restrict__ wgt,
                                              float* __restrict__ xq,
                                              float* __restrict__ qfus,
                                              float* __restrict__ vfus,
                                              float* __restrict__ xout) {
  int blk = blockIdx.x;
  int tid = threadIdx.x;
  if (blk < 8192) {
    // transpose: 64p x 64c tile
    __shared__ float t[64][65];
    int x = blk & 3, y = (blk >> 2) & 31, b = blk >> 7;
    int c0 = y * 64, p0 = x * 64;
    int pl = tid & 63;
    #pragma unroll
    for (int s = 0; s < 16; ++s) {
      int cl = (tid >> 6) + s * 4;
      int p = p0 + pl;
      t[cl][pl] = (p < 196) ? in_v[((size_t)b * 2048 + (c0 + cl)) * 196 + p] : 0.0f;
    }
    __syncthreads();
    int c8 = (tid & 7) * 8;
    #pragma unroll
    for (int s = 0; s < 2; ++s) {
      int p = p0 + (tid >> 3) + s * 32;
      if (p < 196) {
        half8 v;
        #pragma unroll
        for (int j = 0; j < 8; ++j) v[j] = (_Float16)t[c8 + j][(tid >> 3) + s * 32];
        *(half8*)(Vt + ((size_t)b * 196 + p) * 2048 + c0 + c8) = v;
      }
    }
  } else {
    int j = (blk - 8192) * 256 + tid;          // < 2,621,440
    int n = j >> 11;
    Wh[j] = (n < 1200) ? (_Float16)Wv[j] : (_Float16)0.0f;
    if (j < 601088) {
      if (j < 25088)       wgt[j]  = batt[(j / 196) & 1];
      else if (j < 101888) { int i = j - 25088;  xq[i]   = bq_att[i % 1200]; }
      else if (j < 255488) { int i = j - 101888; qfus[i] = bq_fus[i % 2400]; }
      else if (j < 409088) { int i = j - 255488; vfus[i] = bv_fus[i % 2400]; }
      else                 { int i = j - 409088; xout[i] = bc[i % 3000]; }
    }
  }
}

// ---------------- big MFMA GEMM (round-4 structure): 128x128 tile, BK=64,
// XOR-swizzled LDS (0 bank conflicts), __syncthreads barriers, fused
// tanh(acc+bias)*tanh(xq_raw) -> tanh -> Watt projection epilogue (wgt atomics).
__global__ __launch_bounds__(256) void k_gemm1(const _Float16* __restrict__ A,
                                               const _Float16* __restrict__ B,
                                               const float* __restrict__ bias,
                                               const float* __restrict__ xq,
                                               const float* __restrict__ Watt,
                                               float* __restrict__ wgt) {
  __shared__ __align__(16) _Float16 As[128 * 64];
  __shared__ __align__(16) _Float16 Bs[128 * 64];
  int tid = threadIdx.x;
  int n0 = blockIdx.x * 128;   // 10 tiles (padded N=1280)
  int m0 = blockIdx.y * 128;   // 98 tiles, exact
  int lane = tid & 63;
  int wave = tid >> 6;
  int wm = (wave >> 1) * 64;
  int wn = (wave & 1) * 64;
  int fr = lane & 15;
  int fq = lane >> 4;

  int rsub = lane >> 3;
  int gchunk = (lane & 7) ^ rsub;
  const _Float16* aSrc = A + (size_t)(m0 + wave * 8 + rsub) * 2048 + gchunk * 8;
  const _Float16* bSrc = B + (size_t)(n0 + wave * 8 + rsub) * 2048 + gchunk * 8;
  _Float16* aDst = As + (wave * 8) * 64;
  _Float16* bDst = Bs + (wave * 8) * 64;

  f32x4 acc[4][4];
  #pragma unroll
  for (int i = 0; i < 4; ++i)
    #pragma unroll
    for (int j = 0; j < 4; ++j) acc[i][j] = (f32x4){0.f, 0.f, 0.f, 0.f};

  for (int kt = 0; kt < 32; ++kt) {
    int k0 = kt * 64;
    __syncthreads();
    #pragma unroll
    for (int j = 0; j < 4; ++j) {
      gload16(aSrc + k0 + (size_t)j * 32 * 2048, aDst + j * 32 * 64);
      gload16(bSrc + k0 + (size_t)j * 32 * 2048, bDst + j * 32 * 64);
    }
    __syncthreads();
    #pragma unroll
    for (int s = 0; s < 2; ++s) {
      half8 af[4], bf[4];
      #pragma unroll
      for (int mt = 0; mt < 4; ++mt) {
        int row = wm + mt * 16 + fr;
        af[mt] = *(const half8*)(As + row * 64 + (((s * 4 + fq) ^ (fr & 7)) << 3));
      }
      #pragma unroll
      for (int nt = 0; nt < 4; ++nt) {
        int row = wn + nt * 16 + fr;
        bf[nt] = *(const half8*)(Bs + row * 64 + (((s * 4 + fq) ^ (fr & 7)) << 3));
      }
      #pragma unroll
      for (int mt = 0; mt < 4; ++mt)
        #pragma unroll
        for (int nt = 0; nt < 4; ++nt)
          acc[mt][nt] = __builtin_amdgcn_mfma_f32_16x16x32_f16(af[mt], bf[nt], acc[mt][nt], 0, 0, 0);
    }
  }

  float s0[16], s1[16];
  #pragma unroll
  for (int i = 0; i < 16; ++i) { s0[i] = 0.f; s1[i] = 0.f; }

  #pragma unroll
  for (int nt = 0; nt < 4; ++nt) {
    int col = n0 + wn + nt * 16 + fr;
    bool ok = col < 1200;
    float bcol = ok ? bias[col] : 0.f;
    float wa0 = ok ? Watt[col] : 0.f;
    float wa1 = ok ? Watt[1200 + col] : 0.f;
    #pragma unroll
    for (int mt = 0; mt < 4; ++mt) {
      #pragma unroll
      for (int r = 0; r < 4; ++r) {
        int row = m0 + wm + mt * 16 + fq * 4 + r;
        int b = row / 196;
        float xqv = ok ? tanh_fast(xq[b * 1200 + col]) : 0.f;
        float xv = tanh_fast(acc[mt][nt][r] + bcol);
        float xa = tanh_fast(xv * xqv);
        s0[mt * 4 + r] += xa * wa0;
        s1[mt * 4 + r] += xa * wa1;
      }
    }
  }
  #pragma unroll
  for (int i = 0; i < 16; ++i) {
    #pragma unroll
    for (int off = 8; off > 0; off >>= 1) {
      s0[i] += __shfl_down(s0[i], off);
      s1[i] += __shfl_down(s1[i], off);
    }
  }
  if (fr == 0) {
    #pragma unroll
    for (int i = 0; i < 16; ++i) {
      int row = m0 + wm + (i >> 2) * 16 + fq * 4 + (i & 3);
      int b = row / 196;
      int p = row - b * 196;
      atomicAdd(&wgt[(b * 2 + 0) * 196 + p], s0[i]);
      atomicAdd(&wgt[(b * 2 + 1) * 196 + p], s1[i]);
    }
  }
}

// ---------------- v_att[b,g,d] = sum_n softmax(wgt)[b,g,n] * Vt[b,n,d]
__global__ __launch_bounds__(256) void k_vatt(const _Float16* __restrict__ Vt,
                                              const float* __restrict__ wgt,
                                              float* __restrict__ v_att) {
  __shared__ float a0s[196], a1s[196];
  int b = blockIdx.y;
  int tid = threadIdx.x;
  int wv = tid >> 6, lane = tid & 63;
  if (wv < 2) {
    const float* wr = wgt + ((size_t)b * 2 + wv) * 196;
    float v[4];
    #pragma unroll
    for (int i = 0; i < 4; ++i) {
      int n = lane + i * 64;
      v[i] = (n < 196) ? wr[n] : -1e30f;
    }
    float mx = fmaxf(fmaxf(v[0], v[1]), fmaxf(v[2], v[3]));
    #pragma unroll
    for (int off = 32; off > 0; off >>= 1) mx = fmaxf(mx, __shfl_xor(mx, off));
    float s = 0.f;
    #pragma unroll
    for (int i = 0; i < 4; ++i) {
      int n = lane + i * 64;
      float e = (n < 196) ? __expf(v[i] - mx) : 0.f;
      v[i] = e;
      s += e;
    }
    #pragma unroll
    for (int off = 32; off > 0; off >>= 1) s += __shfl_xor(s, off);
    float inv = 1.f / s;
    float* dst = wv ? a1s : a0s;
    #pragma unroll
    for (int i = 0; i < 4; ++i) {
      int n = lane + i * 64;
      if (n < 196) dst[n] = v[i] * inv;
    }
  }
  __syncthreads();
  int d = blockIdx.x * 256 + tid;
  const _Float16* vp = Vt + (size_t)b * 196 * 2048 + d;
  float s0 = 0.f, s1 = 0.f;
  for (int n = 0; n < 196; ++n) {
    float v = (float)vp[(size_t)n * 2048];
    s0 += a0s[n] * v;
    s1 += a1s[n] * v;
  }
  v_att[((size_t)b * 2 + 0) * 2048 + d] = s0;
  v_att[((size_t)b * 2 + 1) * 2048 + d] = s1;
}

// ---------------- merged Q-branch skinny with split-K atomics into pre-biased
// xq_raw / qfus_raw (tanh applied by consumers).
__global__ __launch_bounds__(256) void k_skinnyQ(const float* __restrict__ q,
                                                 const float* __restrict__ Wa,
                                                 const float* __restrict__ Wf,
                                                 int S,
                                                 float* __restrict__ xq,
                                                 float* __restrict__ qfus) {
  __shared__ __align__(16) float As[32][64];
  __shared__ __align__(16) float Ws2[32][64];
  int tid = threadIdx.x;
  int x = blockIdx.x;              // 0..56
  int s = blockIdx.y;
  bool f = x >= 19;
  const float* W = f ? Wf : Wa;
  int nt0 = f ? (x - 19) * 64 : x * 64;
  int N = f ? 2400 : 1200;
  const int K = 2400;
  int tiles = K >> 5;              // 75
  int t0 = (s * tiles) / S;
  int t1 = ((s + 1) * tiles) / S;
  int tx = tid & 15, ty = tid >> 4;
  int lm = tid >> 2;
  int lk = (tid & 3) * 8;
  const float* Ab = q + (size_t)lm * K;
  int ng = nt0 + lm;
  const float* Wb = W + (size_t)ng * K;
  bool wok = ng < N;
  float acc[4][4] = {};
  for (int t = t0; t < t1; ++t) {
    int k0 = t * 32;
    __syncthreads();
    #pragma unroll
    for (int j = 0; j < 8; ++j) As[lk + j][lm] = Ab[k0 + lk + j];
    #pragma unroll
    for (int j = 0; j < 8; ++j) Ws2[lk + j][lm] = wok ? Wb[k0 + lk + j] : 0.0f;
    __syncthreads();
    #pragma unroll
    for (int kk = 0; kk < 32; ++kk) {
      f32x4 a = *(const f32x4*)&As[kk][ty * 4];
      f32x4 wv = *(const f32x4*)&Ws2[kk][tx * 4];
      #pragma unroll
      for (int i = 0; i < 4; ++i)
        #pragma unroll
        for (int j = 0; j < 4; ++j) acc[i][j] += a[i] * wv[j];
    }
  }
  #pragma unroll
  for (int i = 0; i < 4; ++i) {
    int m = ty * 4 + i;
    #pragma unroll
    for (int j = 0; j < 4; ++j) {
      int nl = nt0 + tx * 4 + j;
      if (nl < N) {
        if (f) atomicAdd(&qfus[m * 2400 + nl], acc[i][j]);
        else   atomicAdd(&xq[m * 1200 + nl], acc[i][j]);
      }
    }
  }
}

// ---------------- generic skinny GEMM, split-K atomics into pre-biased Out.
// mode 0: A = A1 ; mode 1: A = tanh(A1)*tanh(A2)
__global__ __launch_bounds__(256) void k_skinny(const float* __restrict__ A1,
                                                const float* __restrict__ A2,
                                                int lda, int strideAz,
                                                const float* __restrict__ W, long strideWz,
                                                int N, int K, int S,
                                                float* __restrict__ Out, int ldOut,
                                                int colOffZ, int mode) {
  __shared__ __align__(16) float As[32][64];
  __shared__ __align__(16) float Ws2[32][64];
  int tid = threadIdx.x;
  int z = blockIdx.z;
  int s = blockIdx.y;
  int nt0 = blockIdx.x * 64;
  int tiles = K >> 5;
  int t0 = (s * tiles) / S;
  int t1 = ((s + 1) * tiles) / S;
  int tx = tid & 15, ty = tid >> 4;
  int lm = tid >> 2;
  int lk = (tid & 3) * 8;
  const float* Ab = A1 + (size_t)z * strideAz + (size_t)lm * lda;
  const float* A2b = A2 ? (A2 + (size_t)z * strideAz + (size_t)lm * lda) : nullptr;
  int ng = nt0 + lm;
  const float* Wb = W + (size_t)z * strideWz + (size_t)ng * K;
  bool wok = ng < N;
  float acc[4][4] = {};
  for (int t = t0; t < t1; ++t) {
    int k0 = t * 32;
    __syncthreads();
    #pragma unroll
    for (int j = 0; j < 8; ++j) {
      float v = Ab[k0 + lk + j];
      if (mode) v = tanh_fast(v) * tanh_fast(A2b[k0 + lk + j]);
      As[lk + j][lm] = v;
    }
    #pragma unroll
    for (int j = 0; j < 8; ++j) Ws2[lk + j][lm] = wok ? Wb[k0 + lk + j] : 0.0f;
    __syncthreads();
    #pragma unroll
    for (int kk = 0; kk < 32; ++kk) {
      f32x4 a = *(const f32x4*)&As[kk][ty * 4];
      f32x4 wv = *(const f32x4*)&Ws2[kk][tx * 4];
      #pragma unroll
      for (int i = 0; i < 4; ++i)
        #pragma unroll
        for (int j = 0; j < 4; ++j) acc[i][j] += a[i] * wv[j];
    }
  }
  #pragma unroll
  for (int i = 0; i < 4; ++i) {
    int m = ty * 4 + i;
    #pragma unroll
    for (int j = 0; j < 4; ++j) {
      int nl = nt0 + tx * 4 + j;
      if (nl < N) atomicAdd(&Out[(size_t)m * ldOut + z * colOffZ + nl], acc[i][j]);
    }
  }
}

extern "C" void kernel_launch(void* const* d_in, const int* in_sizes, int n_in,
                              void* d_out, int out_size, void* d_ws, size_t ws_size,
                              hipStream_t stream) {
  const float* input_q = (const float*)d_in[0];
  const float* input_v = (const float*)d_in[1];
  const float* Wv_att  = (const float*)d_in[2];
  const float* bv_att  = (const float*)d_in[3];
  const float* Wq_att  = (const float*)d_in[4];
  const float* bq_att  = (const float*)d_in[5];
  const float* Watt    = (const float*)d_in[6];
  const float* batt    = (const float*)d_in[7];
  const float* Wv_fus  = (const float*)d_in[8];
  const float* bv_fus  = (const float*)d_in[9];
  const float* Wq_fus  = (const float*)d_in[10];
  const float* bq_fus  = (const float*)d_in[11];
  const float* Wc      = (const float*)d_in[12];
  const float* bc      = (const float*)d_in[13];
  float* out = (float*)d_out;

  char* ws = (char*)d_ws;
  _Float16* Vt   = (_Float16*)ws; ws += 51380224;   // 64*196*2048 fp16
  _Float16* Wh   = (_Float16*)ws; ws += 5242880;    // 1280*2048 fp16
  float* xq      = (float*)ws;    ws += 307200;     // 64*1200 f32 (raw, pre-biased)
  float* v_att   = (float*)ws;    ws += 1048576;    // 64*2*2048 f32
  float* v_fus   = (float*)ws;    ws += 614400;     // 64*2400 f32 (raw, pre-biased)
  float* q_fus   = (float*)ws;    ws += 614400;     // 64*2400 f32 (raw, pre-biased)

  float* x_out   = out;            // [64][3000] (pre-biased with bc)
  float* wgt_out = out + 192000;   // [64][2][196] (pre-biased with batt)

  const int S = 8;

  // 1: transpose + Wh convert + all bias inits
  k_misc<<<dim3(18432), dim3(256), 0, stream>>>(input_v, Vt, Wv_att, Wh,
                                                batt, bq_att, bq_fus, bv_fus, bc,
                                                wgt_out, xq, q_fus, v_fus, x_out);

  // 2: Q-branch raw sums (atomics into pre-biased xq / q_fus)
  k_skinnyQ<<<dim3(57, S), dim3(256), 0, stream>>>(input_q, Wq_att, Wq_fus, S, xq, q_fus);

  // 3: fused big GEMM -> wgt (output 1); xatt never materialized
  k_gemm1<<<dim3(10, 98), dim3(256), 0, stream>>>(Vt, Wh, bv_att, xq, Watt, wgt_out);

  // 4: softmax (fused) + v_att
  k_vatt<<<dim3(8, 64), dim3(256), 0, stream>>>(Vt, wgt_out, v_att);

  // 5: v_fus raw sums (atomics into pre-biased v_fus)
  k_skinny<<<dim3(19, S, 2), dim3(256), 0, stream>>>(v_att, nullptr, 4096, 2048,
                                                     Wv_fus, 1200L * 2048L, 1200, 2048, S,
                                                     v_fus, 2400, 1200, 0);

  // 6: x = (tanh(v_fus)*tanh(q_fus)) @ Wc^T (+bc pre-biased)  (output 0)
  k_skinny<<<dim3(47, S, 1), dim3(256), 0, stream>>>(v_fus, q_fus, 2400, 0,
                                                     Wc, 0, 3000, 2400, S,
                                                     x_out, 3000, 0, 1);
}